// Round 5
// baseline (248.949 us; speedup 1.0000x reference)
//
#include <hip/hip_runtime.h>
#include <hip/hip_bf16.h>

#define D 512

typedef __attribute__((ext_vector_type(8))) short bf16x8;
typedef __attribute__((ext_vector_type(4))) float f32x4;

__device__ inline float b2f(short h) {
    union { unsigned u; float f; } c;
    c.u = ((unsigned)(unsigned short)h) << 16;
    return c.f;
}

__device__ __forceinline__ void stage16(const void* g, void* l) {
    __builtin_amdgcn_global_load_lds((const __attribute__((address_space(1))) void*)g,
                                     (__attribute__((address_space(3))) void*)l, 16, 0, 0);
}

// ---------------- degree histograms ----------------
__global__ void k_hist(const int* __restrict__ src, const int* __restrict__ dst,
                       int* __restrict__ deg_out, int* __restrict__ deg_in, int E) {
    int e = blockIdx.x * 256 + threadIdx.x;
    if (e < E) {
        atomicAdd(&deg_out[src[e]], 1);
        atomicAdd(&deg_in[dst[e]], 1);
    }
}

// ---------------- pre-scale x by rsqrt(deg_out) -> bf16 xs ----------------
__global__ __launch_bounds__(256)
void k_scale(const float* __restrict__ x, const int* __restrict__ deg_out,
             __hip_bfloat16* __restrict__ xs, int total16) {
    int i = blockIdx.x * 256 + threadIdx.x;   // one thread = 8 elements
    if (i >= total16) return;
    int node = i >> 6;
    float w = rsqrtf((float)max(deg_out[node], 1));
    const float4* p = (const float4*)(x + (size_t)i * 8);
    float4 a = p[0], b = p[1];
    union { float4 f4; __hip_bfloat16 h[8]; } o;
    o.h[0] = __float2bfloat16(a.x * w);
    o.h[1] = __float2bfloat16(a.y * w);
    o.h[2] = __float2bfloat16(a.z * w);
    o.h[3] = __float2bfloat16(a.w * w);
    o.h[4] = __float2bfloat16(b.x * w);
    o.h[5] = __float2bfloat16(b.y * w);
    o.h[6] = __float2bfloat16(b.z * w);
    o.h[7] = __float2bfloat16(b.w * w);
    *(float4*)(xs + (size_t)i * 8) = o.f4;
}

// ---------------- exclusive scan of deg_in -> row_start ----------------
__global__ void k_scan1(const int* __restrict__ deg_in, int* __restrict__ row_start,
                        int* __restrict__ partials, int N) {
    __shared__ int sm[1024];
    int tid = threadIdx.x;
    int i = blockIdx.x * 1024 + tid;
    int v = (i < N) ? deg_in[i] : 0;
    sm[tid] = v;
    __syncthreads();
    int acc = v;
    #pragma unroll
    for (int off = 1; off < 1024; off <<= 1) {
        int t = (tid >= off) ? sm[tid - off] : 0;
        __syncthreads();
        acc += t;
        sm[tid] = acc;
        __syncthreads();
    }
    if (i < N) row_start[i] = acc - v;
    if (tid == 1023) partials[blockIdx.x] = acc;
}

__global__ void k_scan2w(int* __restrict__ partials, int* __restrict__ row_start,
                         int nb, int N) {
    int lane = threadIdx.x;
    int orig = (lane < nb) ? partials[lane] : 0;
    int v = orig;
    #pragma unroll
    for (int off = 1; off < 64; off <<= 1) {
        int t = __shfl_up(v, off, 64);
        if (lane >= off) v += t;
    }
    if (lane < nb) partials[lane] = v - orig;
    if (lane == 63) row_start[N] = v;
}

__global__ void k_scan2s(int* __restrict__ partials, int* __restrict__ row_start,
                         int nb, int N) {
    if (threadIdx.x == 0 && blockIdx.x == 0) {
        int run = 0;
        for (int b = 0; b < nb; b++) { int t = partials[b]; partials[b] = run; run += t; }
        row_start[N] = run;
    }
}

__global__ void k_scan3(int* __restrict__ row_start, const int* __restrict__ partials, int N) {
    int i = blockIdx.x * 256 + threadIdx.x;
    if (i < N) row_start[i] += partials[i >> 10];
}

// ---------------- CSR bucket fill ----------------
__global__ void k_fill(const int* __restrict__ src, const int* __restrict__ dst,
                       const int* __restrict__ row_start, int* __restrict__ cursor,
                       int* __restrict__ csr_src, int E) {
    int e = blockIdx.x * 256 + threadIdx.x;
    if (e < E) {
        int d = dst[e];
        int slot = atomicAdd(&cursor[d], 1);
        csr_src[row_start[d] + slot] = src[e];
    }
}

// ---------------- SpMM over bf16 pre-scaled rows ----------------
__global__ __launch_bounds__(256)
void k_spmm(const __hip_bfloat16* __restrict__ xs, const int* __restrict__ row_start,
            const int* __restrict__ csr_src, __hip_bfloat16* __restrict__ A, int N) {
    int wid = threadIdx.x >> 6;
    int lane = threadIdx.x & 63;
    int node = blockIdx.x * 4 + wid;
    if (node >= N) return;
    int rs = row_start[node], re = row_start[node + 1];

    float acc[8];
    #pragma unroll
    for (int k = 0; k < 8; k++) acc[k] = 0.f;
    const __hip_bfloat16* xl = xs + (size_t)lane * 8;

    int j = rs;
    for (; j + 4 <= re; j += 4) {
        int s0 = csr_src[j], s1 = csr_src[j + 1], s2 = csr_src[j + 2], s3 = csr_src[j + 3];
        bf16x8 v0 = *(const bf16x8*)(xl + (size_t)s0 * D);
        bf16x8 v1 = *(const bf16x8*)(xl + (size_t)s1 * D);
        bf16x8 v2 = *(const bf16x8*)(xl + (size_t)s2 * D);
        bf16x8 v3 = *(const bf16x8*)(xl + (size_t)s3 * D);
        #pragma unroll
        for (int k = 0; k < 8; k++)
            acc[k] += (b2f(v0[k]) + b2f(v1[k])) + (b2f(v2[k]) + b2f(v3[k]));
    }
    for (; j < re; j++) {
        int s = csr_src[j];
        bf16x8 v = *(const bf16x8*)(xl + (size_t)s * D);
        #pragma unroll
        for (int k = 0; k < 8; k++) acc[k] += b2f(v[k]);
    }

    float rn = rsqrtf((float)max(re - rs, 1));
    union { float4 f4; __hip_bfloat16 h[8]; } o;
    #pragma unroll
    for (int k = 0; k < 8; k++) o.h[k] = __float2bfloat16(acc[k] * rn);
    *(float4*)(A + (size_t)node * D + lane * 8) = o.f4;
}

// ---------------- f32 fallback SpMM ----------------
__global__ __launch_bounds__(256)
void k_spmm_f32(const float* __restrict__ x, const int* __restrict__ row_start,
                const int* __restrict__ csr_src, const int* __restrict__ deg_out,
                __hip_bfloat16* __restrict__ A, int N) {
    int wid = threadIdx.x >> 6;
    int lane = threadIdx.x & 63;
    int node = blockIdx.x * 4 + wid;
    if (node >= N) return;
    int rs = row_start[node], re = row_start[node + 1];
    float4 acc0 = {0.f, 0.f, 0.f, 0.f};
    float4 acc1 = {0.f, 0.f, 0.f, 0.f};
    const float* xl = x + (size_t)lane * 8;
    for (int j = rs; j < re; j++) {
        int s = csr_src[j];
        float w = rsqrtf((float)max(deg_out[s], 1));
        const float4* p = (const float4*)(xl + (size_t)s * D);
        float4 a = p[0], b = p[1];
        acc0.x += a.x * w; acc0.y += a.y * w; acc0.z += a.z * w; acc0.w += a.w * w;
        acc1.x += b.x * w; acc1.y += b.y * w; acc1.z += b.z * w; acc1.w += b.w * w;
    }
    float rn = rsqrtf((float)max(re - rs, 1));
    union { float4 f4; __hip_bfloat16 h[8]; } o;
    o.h[0] = __float2bfloat16(acc0.x * rn);
    o.h[1] = __float2bfloat16(acc0.y * rn);
    o.h[2] = __float2bfloat16(acc0.z * rn);
    o.h[3] = __float2bfloat16(acc0.w * rn);
    o.h[4] = __float2bfloat16(acc1.x * rn);
    o.h[5] = __float2bfloat16(acc1.y * rn);
    o.h[6] = __float2bfloat16(acc1.z * rn);
    o.h[7] = __float2bfloat16(acc1.w * rn);
    *(float4*)(A + (size_t)node * D + lane * 8) = o.f4;
}

// ---------------- pack W into per-col-chunk MFMA B layout ----------------
// bid = c*128 + kt*8 + ntc ; element (bid, lane, j) =
//   W[kt*32 + (lane>>4)*8 + j][(c*8 + ntc)*16 + (lane&15)]
// => each c-chunk (128KB) is contiguous; k_gemm2 block copies one chunk to LDS.
__global__ void k_packw2(const float* __restrict__ W, __hip_bfloat16* __restrict__ Wp) {
    int bid = blockIdx.x;        // 0..511
    int c = bid >> 7, kt = (bid >> 3) & 15, ntc = bid & 7;
    int lane = threadIdx.x;      // 0..63
    int k0 = kt * 32 + (lane >> 4) * 8;
    int n  = (c * 8 + ntc) * 16 + (lane & 15);
    union { float4 f4; __hip_bfloat16 h[8]; } o;
    #pragma unroll
    for (int j = 0; j < 8; j++)
        o.h[j] = __float2bfloat16(W[(size_t)(k0 + j) * D + n]);
    *(float4*)(Wp + ((size_t)bid * 64 + lane) * 8) = o.f4;
}

// legacy pack (fallback path)
__global__ void k_packw(const float* __restrict__ W, __hip_bfloat16* __restrict__ Wp) {
    int tile = blockIdx.x;
    int lane = threadIdx.x;
    int kt = tile >> 5, nt = tile & 31;
    int k0 = kt * 32 + (lane >> 4) * 8;
    int n  = nt * 16 + (lane & 15);
    union { float4 f4; __hip_bfloat16 h[8]; } o;
    #pragma unroll
    for (int j = 0; j < 8; j++)
        o.h[j] = __float2bfloat16(W[(size_t)(k0 + j) * D + n]);
    *(float4*)(Wp + ((size_t)tile * 64 + lane) * 8) = o.f4;
}

// ---------------- pass A: W-stationary GEMM, h = A@W + b (bf16) ----------------
// grid = 256 blocks: cch = bid&3 (128-col chunk), rgrp = bid>>2 (row group).
// 512 thr = 8 waves = 4 row-groups x 2 col-halves. W chunk (128KB) resident in LDS.
// A streamed in 192-row tiles, K-sliced (kt of 32), double-buffered 2x12KB.
__global__ __launch_bounds__(512, 2)
void k_gemm2(const __hip_bfloat16* __restrict__ A, const __hip_bfloat16* __restrict__ Wp,
             const float* __restrict__ bias, __hip_bfloat16* __restrict__ h, int M) {
    __shared__ __align__(16) char lds[131072 + 2 * 12288];
    char* ldsW = lds;
    char* ldsA = lds + 131072;   // [buf][elem = j*192 + row] * 16B

    int tid = threadIdx.x;
    int wid = tid >> 6, lane = tid & 63;
    int wr = wid >> 1, wc = wid & 1;
    int l4 = lane >> 4, coll = lane & 15;
    int cch = blockIdx.x & 3;
    int rgrp = blockIdx.x >> 2;

    // ---- load W chunk (128KB) once: 16 rounds x 512thr x 16B ----
    {
        const char* g = (const char*)Wp + (size_t)cch * 131072 + (size_t)wid * 1024 + lane * 16;
        char* l = ldsW + wid * 1024;   // HW adds lane*16
        #pragma unroll
        for (int r = 0; r < 16; r++)
            stage16(g + r * 8192, l + r * 8192);
    }

    // per-wave A-stage plan: instrs s (0..11): j = s/3, rowblk = s%3
    // waves 0..3 issue s=wid and s=wid+4; waves 4..7 issue s=wid+4 only.
    int s0 = (wid < 4) ? wid : wid + 4;
    int j0 = s0 / 3, rb0 = s0 % 3;
    int s1 = wid + 4;                    // only used when wid<4
    int j1 = s1 / 3, rb1 = s1 % 3;

    // bias for this thread's 4 columns
    float bia[4];
    #pragma unroll
    for (int ni = 0; ni < 4; ni++)
        bia[ni] = bias[cch * 128 + wc * 64 + ni * 16 + coll];

    int ntiles = (M + 191) / 192;

    auto stageA = [&](int tb, int kt, int buf) {
        char* bb = ldsA + buf * 12288;
        {
            int grow = tb + rb0 * 64 + lane;
            if (grow > M - 1) grow = M - 1;
            stage16((const char*)A + (size_t)grow * 1024 + kt * 64 + j0 * 16,
                    bb + s0 * 1024);
        }
        if (wid < 4) {
            int grow = tb + rb1 * 64 + lane;
            if (grow > M - 1) grow = M - 1;
            stage16((const char*)A + (size_t)grow * 1024 + kt * 64 + j1 * 16,
                    bb + s1 * 1024);
        }
    };

    for (int t = rgrp; t < ntiles; t += 64) {
        int tb = t * 192;
        stageA(tb, 0, 0);
        stageA(tb, 1, 1);
        if (wid < 4) { asm volatile("s_waitcnt vmcnt(2)" ::: "memory"); }
        else         { asm volatile("s_waitcnt vmcnt(1)" ::: "memory"); }
        __builtin_amdgcn_sched_barrier(0);
        __builtin_amdgcn_s_barrier();

        f32x4 acc[3][4];
        #pragma unroll
        for (int ai = 0; ai < 3; ai++)
            #pragma unroll
            for (int ni = 0; ni < 4; ni++) acc[ai][ni] = (f32x4){0.f, 0.f, 0.f, 0.f};

        #pragma unroll
        for (int kt = 0; kt < 14; kt++) {
            int cur = kt & 1;
            char* aw = ldsA + cur * 12288 + l4 * 3072 + (wr * 48 + coll) * 16;
            bf16x8 af[3];
            #pragma unroll
            for (int ai = 0; ai < 3; ai++)
                af[ai] = *(const bf16x8*)(aw + ai * 256);
            char* ww = ldsW + (((kt * 8 + wc * 4) * 64) + lane) * 16;
            bf16x8 bf[4];
            #pragma unroll
            for (int ni = 0; ni < 4; ni++)
                bf[ni] = *(const bf16x8*)(ww + ni * 1024);
            asm volatile("s_waitcnt lgkmcnt(0)" ::: "memory");
            __builtin_amdgcn_sched_barrier(0);
            __builtin_amdgcn_s_barrier();            // all waves done reading buf[cur]
            stageA(tb, kt + 2, cur);                 // overwrite with tile kt+2
            #pragma unroll
            for (int ai = 0; ai < 3; ai++)
                #pragma unroll
                for (int ni = 0; ni < 4; ni++)
                    acc[ai][ni] = __builtin_amdgcn_mfma_f32_16x16x32_bf16(af[ai], bf[ni], acc[ai][ni], 0, 0, 0);
            if (wid < 4) { asm volatile("s_waitcnt vmcnt(2)" ::: "memory"); }
            else         { asm volatile("s_waitcnt vmcnt(1)" ::: "memory"); }
            __builtin_amdgcn_sched_barrier(0);
            __builtin_amdgcn_s_barrier();            // tile kt+1 staged
        }
        // kt = 14 (reads buf0; no stage; drain to 0 so kt15 readable)
        {
            char* aw = ldsA + 0 * 12288 + l4 * 3072 + (wr * 48 + coll) * 16;
            bf16x8 af[3];
            #pragma unroll
            for (int ai = 0; ai < 3; ai++) af[ai] = *(const bf16x8*)(aw + ai * 256);
            char* ww = ldsW + (((14 * 8 + wc * 4) * 64) + lane) * 16;
            #pragma unroll
            for (int ni = 0; ni < 4; ni++) {
                bf16x8 bf = *(const bf16x8*)(ww + ni * 1024);
                #pragma unroll
                for (int ai = 0; ai < 3; ai++)
                    acc[ai][ni] = __builtin_amdgcn_mfma_f32_16x16x32_bf16(af[ai], bf, acc[ai][ni], 0, 0, 0);
            }
            asm volatile("s_waitcnt vmcnt(0)" ::: "memory");
            __builtin_amdgcn_sched_barrier(0);
            __builtin_amdgcn_s_barrier();
        }
        // kt = 15 (reads buf1; barrier after lgkm protects next tile's staging)
        {
            char* aw = ldsA + 1 * 12288 + l4 * 3072 + (wr * 48 + coll) * 16;
            bf16x8 af[3];
            #pragma unroll
            for (int ai = 0; ai < 3; ai++) af[ai] = *(const bf16x8*)(aw + ai * 256);
            char* ww = ldsW + (((15 * 8 + wc * 4) * 64) + lane) * 16;
            bf16x8 bf[4];
            #pragma unroll
            for (int ni = 0; ni < 4; ni++) bf[ni] = *(const bf16x8*)(ww + ni * 1024);
            asm volatile("s_waitcnt lgkmcnt(0)" ::: "memory");
            __builtin_amdgcn_sched_barrier(0);
            __builtin_amdgcn_s_barrier();
            #pragma unroll
            for (int ai = 0; ai < 3; ai++)
                #pragma unroll
                for (int ni = 0; ni < 4; ni++)
                    acc[ai][ni] = __builtin_amdgcn_mfma_f32_16x16x32_bf16(af[ai], bf[ni], acc[ai][ni], 0, 0, 0);
        }

        // write h tile (bf16, bias added)
        #pragma unroll
        for (int ai = 0; ai < 3; ai++) {
            #pragma unroll
            for (int r = 0; r < 4; r++) {
                int row = tb + wr * 48 + ai * 16 + l4 * 4 + r;
                if (row < M) {
                    __hip_bfloat16* hp = h + (size_t)row * D + cch * 128 + wc * 64 + coll;
                    #pragma unroll
                    for (int ni = 0; ni < 4; ni++)
                        hp[ni * 16] = __float2bfloat16(acc[ai][ni][r] + bia[ni]);
                }
            }
        }
    }
}

// ---------------- pass B: LayerNorm + tanh-GELU (one wave per row) ----------------
__global__ __launch_bounds__(256)
void k_lngelu(const __hip_bfloat16* __restrict__ h, const float* __restrict__ gamma,
              const float* __restrict__ beta, float* __restrict__ out, int M) {
    int gw = (blockIdx.x * 256 + threadIdx.x) >> 6;
    int lane = threadIdx.x & 63;
    int nw = (gridDim.x * 256) >> 6;

    float g8[8], b8[8];
    #pragma unroll
    for (int k = 0; k < 8; k++) {
        g8[k] = gamma[lane * 8 + k];
        b8[k] = beta[lane * 8 + k];
    }

    for (int row = gw; row < M; row += nw) {
        bf16x8 v = *(const bf16x8*)(h + (size_t)row * D + lane * 8);
        float f[8];
        float s = 0.f, q = 0.f;
        #pragma unroll
        for (int k = 0; k < 8; k++) {
            f[k] = b2f(v[k]);
            s += f[k]; q += f[k] * f[k];
        }
        #pragma unroll
        for (int off = 1; off < 64; off <<= 1) {
            s += __shfl_xor(s, off, 64);
            q += __shfl_xor(q, off, 64);
        }
        float mean = s * (1.0f / 512.0f);
        float var = q * (1.0f / 512.0f) - mean * mean;
        float rstd = rsqrtf(fmaxf(var, 0.f) + 1e-5f);
        float o[8];
        #pragma unroll
        for (int k = 0; k < 8; k++) {
            float y = (f[k] - mean) * rstd * g8[k] + b8[k];
            float yy = y * y;
            float pz = fmaf(yy, -0.1029423374f, -2.3022076728f);
            float e = __builtin_amdgcn_exp2f(y * pz);
            o[k] = y * __builtin_amdgcn_rcpf(1.0f + e);
        }
        float* orow = out + (size_t)row * D + lane * 8;
        *(float4*)orow = (float4){o[0], o[1], o[2], o[3]};
        *(float4*)(orow + 4) = (float4){o[4], o[5], o[6], o[7]};
    }
}

// ---------------- legacy fused GEMM (fallback if ws too small) ----------------
__global__ __launch_bounds__(512)
void k_gemm(const __hip_bfloat16* __restrict__ A, const __hip_bfloat16* __restrict__ Wp,
            const float* __restrict__ bias, const float* __restrict__ gamma,
            const float* __restrict__ beta, float* __restrict__ out, int M) {
    int tid = threadIdx.x;
    int wid = tid >> 6, lane = tid & 63;
    int wm = wid >> 2;
    int wn = wid & 3;
    int l4 = lane >> 4, coll = lane & 15;
    int m0 = blockIdx.x * 32 + wm * 16;
    int arow = m0 + coll;
    bool rowok = (arow < M);

    f32x4 acc[8];
    #pragma unroll
    for (int t = 0; t < 8; t++) acc[t] = (f32x4){0.f, 0.f, 0.f, 0.f};

    const bf16x8* wpb = (const bf16x8*)Wp;
    for (int kt = 0; kt < 16; kt++) {
        bf16x8 afrag;
        if (rowok) afrag = *(const bf16x8*)(A + (size_t)arow * D + kt * 32 + l4 * 8);
        else afrag = (bf16x8){0,0,0,0,0,0,0,0};
        const bf16x8* wp = wpb + ((size_t)(kt * 32 + wn * 8) * 64 + lane);
        #pragma unroll
        for (int t = 0; t < 8; t++) {
            bf16x8 bfrag = wp[(size_t)t * 64];
            acc[t] = __builtin_amdgcn_mfma_f32_16x16x32_bf16(afrag, bfrag, acc[t], 0, 0, 0);
        }
    }
    __shared__ float s_sum[32][4];
    __shared__ float s_sq[32][4];
    #pragma unroll
    for (int r = 0; r < 4; r++) {
        float s = 0.f, q = 0.f;
        #pragma unroll
        for (int t = 0; t < 8; t++) {
            int col = wn * 128 + t * 16 + coll;
            float v = acc[t][r] + bias[col];
            acc[t][r] = v;
            s += v; q += v * v;
        }
        #pragma unroll
        for (int off = 1; off < 16; off <<= 1) {
            s += __shfl_xor(s, off, 64);
            q += __shfl_xor(q, off, 64);
        }
        if (coll == 0) {
            int rb = wm * 16 + l4 * 4 + r;
            s_sum[rb][wn] = s;
            s_sq[rb][wn] = q;
        }
    }
    __syncthreads();
    #pragma unroll
    for (int r = 0; r < 4; r++) {
        int rb = wm * 16 + l4 * 4 + r;
        int gr = blockIdx.x * 32 + rb;
        if (gr >= M) continue;
        float s = s_sum[rb][0] + s_sum[rb][1] + s_sum[rb][2] + s_sum[rb][3];
        float q = s_sq[rb][0] + s_sq[rb][1] + s_sq[rb][2] + s_sq[rb][3];
        float mean = s * (1.0f / 512.0f);
        float var = q * (1.0f / 512.0f) - mean * mean;
        float rstd = rsqrtf(fmaxf(var, 0.f) + 1e-5f);
        #pragma unroll
        for (int t = 0; t < 8; t++) {
            int col = wn * 128 + t * 16 + coll;
            float y = (acc[t][r] - mean) * rstd * gamma[col] + beta[col];
            float yy = y * y;
            float pz = fmaf(yy, -0.1029423374f, -2.3022076728f);
            float e = __builtin_amdgcn_exp2f(y * pz);
            out[(size_t)gr * D + col] = y * __builtin_amdgcn_rcpf(1.0f + e);
        }
    }
}

extern "C" void kernel_launch(void* const* d_in, const int* in_sizes, int n_in,
                              void* d_out, int out_size, void* d_ws, size_t ws_size,
                              hipStream_t stream) {
    const float* x     = (const float*)d_in[0];
    const float* W     = (const float*)d_in[1];
    const float* b     = (const float*)d_in[2];
    const float* gamma = (const float*)d_in[3];
    const float* beta  = (const float*)d_in[4];
    const int*   src   = (const int*)d_in[5];
    const int*   dst   = (const int*)d_in[6];
    int N = in_sizes[0] / D;
    int E = in_sizes[5];
    float* out = (float*)d_out;

    int* deg_out   = (int*)d_ws;                 // N
    int* deg_in    = deg_out + N;                // N
    int* row_start = deg_in + N;                 // N+1
    int* cursor    = row_start + N + 1;          // N
    int* partials  = cursor + N;                 // <=64
    int* csr_src   = partials + 64;              // E
    uintptr_t p = (uintptr_t)(csr_src + E);
    p = (p + 255) & ~(uintptr_t)255;
    __hip_bfloat16* A = (__hip_bfloat16*)p;      // N*D bf16
    p += (size_t)N * D * sizeof(__hip_bfloat16);
    p = (p + 255) & ~(uintptr_t)255;
    __hip_bfloat16* Wp = (__hip_bfloat16*)p;     // D*D bf16
    p += (size_t)D * D * sizeof(__hip_bfloat16);
    p = (p + 255) & ~(uintptr_t)255;
    __hip_bfloat16* xs = (__hip_bfloat16*)p;     // N*D bf16 (xs, later reused as h)
    size_t need_xs = (p - (uintptr_t)d_ws) + (size_t)N * D * sizeof(__hip_bfloat16);
    bool use_bf16_path = (ws_size >= need_xs);

    hipMemsetAsync(deg_out, 0, (size_t)2 * N * sizeof(int), stream);
    hipMemsetAsync(cursor, 0, (size_t)N * sizeof(int), stream);

    k_hist<<<(E + 255) / 256, 256, 0, stream>>>(src, dst, deg_out, deg_in, E);
    int nb1 = (N + 1023) / 1024;
    k_scan1<<<nb1, 1024, 0, stream>>>(deg_in, row_start, partials, N);
    if (nb1 <= 64)
        k_scan2w<<<1, 64, 0, stream>>>(partials, row_start, nb1, N);
    else
        k_scan2s<<<1, 64, 0, stream>>>(partials, row_start, nb1, N);
    k_scan3<<<(N + 255) / 256, 256, 0, stream>>>(row_start, partials, N);
    k_fill<<<(E + 255) / 256, 256, 0, stream>>>(src, dst, row_start, cursor, csr_src, E);

    if (use_bf16_path) {
        int total16 = N * 64;
        k_scale<<<(total16 + 255) / 256, 256, 0, stream>>>(x, deg_out, xs, total16);
        k_spmm<<<(N + 3) / 4, 256, 0, stream>>>(xs, row_start, csr_src, A, N);
        k_packw2<<<512, 64, 0, stream>>>(W, Wp);
        __hip_bfloat16* h = xs;   // xs dead after k_spmm; reuse as h
        k_gemm2<<<256, 512, 0, stream>>>(A, Wp, b, h, N);
        k_lngelu<<<1024, 256, 0, stream>>>(h, gamma, beta, out, N);
    } else {
        k_spmm_f32<<<(N + 3) / 4, 256, 0, stream>>>(x, row_start, csr_src, deg_out, A, N);
        k_packw<<<512, 64, 0, stream>>>(W, Wp);
        k_gemm<<<(N + 31) / 32, 512, 0, stream>>>(A, Wp, b, gamma, beta, out, N);
    }
}

// Round 6
// 240.558 us; speedup vs baseline: 1.0349x; 1.0349x over previous
//
#include <hip/hip_runtime.h>
#include <hip/hip_bf16.h>

#define D 512

typedef __attribute__((ext_vector_type(8))) short bf16x8;
typedef __attribute__((ext_vector_type(4))) float f32x4;

__device__ inline float b2f(short h) {
    union { unsigned u; float f; } c;
    c.u = ((unsigned)(unsigned short)h) << 16;
    return c.f;
}

// ---------------- degree histograms ----------------
__global__ void k_hist(const int* __restrict__ src, const int* __restrict__ dst,
                       int* __restrict__ deg_out, int* __restrict__ deg_in, int E) {
    int e = blockIdx.x * 256 + threadIdx.x;
    if (e < E) {
        atomicAdd(&deg_out[src[e]], 1);
        atomicAdd(&deg_in[dst[e]], 1);
    }
}

// ---------------- pre-scale x by rsqrt(deg_out) -> bf16 xs ----------------
__global__ __launch_bounds__(256)
void k_scale(const float* __restrict__ x, const int* __restrict__ deg_out,
             __hip_bfloat16* __restrict__ xs, int total16) {
    int i = blockIdx.x * 256 + threadIdx.x;   // one thread = 8 elements
    if (i >= total16) return;
    int node = i >> 6;
    float w = rsqrtf((float)max(deg_out[node], 1));
    const float4* p = (const float4*)(x + (size_t)i * 8);
    float4 a = p[0], b = p[1];
    union { float4 f4; __hip_bfloat16 h[8]; } o;
    o.h[0] = __float2bfloat16(a.x * w);
    o.h[1] = __float2bfloat16(a.y * w);
    o.h[2] = __float2bfloat16(a.z * w);
    o.h[3] = __float2bfloat16(a.w * w);
    o.h[4] = __float2bfloat16(b.x * w);
    o.h[5] = __float2bfloat16(b.y * w);
    o.h[6] = __float2bfloat16(b.z * w);
    o.h[7] = __float2bfloat16(b.w * w);
    *(float4*)(xs + (size_t)i * 8) = o.f4;
}

// ---------------- exclusive scan of deg_in -> row_start ----------------
__global__ void k_scan1(const int* __restrict__ deg_in, int* __restrict__ row_start,
                        int* __restrict__ partials, int N) {
    __shared__ int sm[1024];
    int tid = threadIdx.x;
    int i = blockIdx.x * 1024 + tid;
    int v = (i < N) ? deg_in[i] : 0;
    sm[tid] = v;
    __syncthreads();
    int acc = v;
    #pragma unroll
    for (int off = 1; off < 1024; off <<= 1) {
        int t = (tid >= off) ? sm[tid - off] : 0;
        __syncthreads();
        acc += t;
        sm[tid] = acc;
        __syncthreads();
    }
    if (i < N) row_start[i] = acc - v;
    if (tid == 1023) partials[blockIdx.x] = acc;
}

__global__ void k_scan2w(int* __restrict__ partials, int* __restrict__ row_start,
                         int nb, int N) {
    int lane = threadIdx.x;
    int orig = (lane < nb) ? partials[lane] : 0;
    int v = orig;
    #pragma unroll
    for (int off = 1; off < 64; off <<= 1) {
        int t = __shfl_up(v, off, 64);
        if (lane >= off) v += t;
    }
    if (lane < nb) partials[lane] = v - orig;
    if (lane == 63) row_start[N] = v;
}

__global__ void k_scan2s(int* __restrict__ partials, int* __restrict__ row_start,
                         int nb, int N) {
    if (threadIdx.x == 0 && blockIdx.x == 0) {
        int run = 0;
        for (int b = 0; b < nb; b++) { int t = partials[b]; partials[b] = run; run += t; }
        row_start[N] = run;
    }
}

__global__ void k_scan3(int* __restrict__ row_start, const int* __restrict__ partials, int N) {
    int i = blockIdx.x * 256 + threadIdx.x;
    if (i < N) row_start[i] += partials[i >> 10];
}

// ---------------- CSR bucket fill ----------------
__global__ void k_fill(const int* __restrict__ src, const int* __restrict__ dst,
                       const int* __restrict__ row_start, int* __restrict__ cursor,
                       int* __restrict__ csr_src, int E) {
    int e = blockIdx.x * 256 + threadIdx.x;
    if (e < E) {
        int d = dst[e];
        int slot = atomicAdd(&cursor[d], 1);
        csr_src[row_start[d] + slot] = src[e];
    }
}

// ---------------- SpMM: gather bf16 rows, write A in FRAGMENT-MAJOR layout ----------------
// A'[rg][kt][l4][coll] (16B chunks): rg = node/16, coll = node%16; chunk (kt,l4) holds
// k = kt*32 + l4*8 .. +8.  Lane l's 16B output (k = 8l..8l+7) lands at chunk index l
// => dest16 = rg*1024 + l*16 + coll.  Block = 1024 thr = 16 waves = one full rg, so
// all 16 chunks of each 256B region are written by one block (one XCD's L2).
__global__ __launch_bounds__(1024)
void k_spmm(const __hip_bfloat16* __restrict__ xs, const int* __restrict__ row_start,
            const int* __restrict__ csr_src, __hip_bfloat16* __restrict__ Ap, int N) {
    int wid = threadIdx.x >> 6;     // 0..15 = node within rg
    int lane = threadIdx.x & 63;
    int node = blockIdx.x * 16 + wid;
    if (node >= N) return;
    int rs = row_start[node], re = row_start[node + 1];

    float acc[8];
    #pragma unroll
    for (int k = 0; k < 8; k++) acc[k] = 0.f;
    const __hip_bfloat16* xl = xs + (size_t)lane * 8;

    int j = rs;
    for (; j + 4 <= re; j += 4) {
        int s0 = csr_src[j], s1 = csr_src[j + 1], s2 = csr_src[j + 2], s3 = csr_src[j + 3];
        bf16x8 v0 = *(const bf16x8*)(xl + (size_t)s0 * D);
        bf16x8 v1 = *(const bf16x8*)(xl + (size_t)s1 * D);
        bf16x8 v2 = *(const bf16x8*)(xl + (size_t)s2 * D);
        bf16x8 v3 = *(const bf16x8*)(xl + (size_t)s3 * D);
        #pragma unroll
        for (int k = 0; k < 8; k++)
            acc[k] += (b2f(v0[k]) + b2f(v1[k])) + (b2f(v2[k]) + b2f(v3[k]));
    }
    for (; j < re; j++) {
        int s = csr_src[j];
        bf16x8 v = *(const bf16x8*)(xl + (size_t)s * D);
        #pragma unroll
        for (int k = 0; k < 8; k++) acc[k] += b2f(v[k]);
    }

    float rn = rsqrtf((float)max(re - rs, 1));
    union { float4 f4; __hip_bfloat16 h[8]; } o;
    #pragma unroll
    for (int k = 0; k < 8; k++) o.h[k] = __float2bfloat16(acc[k] * rn);
    *(float4*)((char*)Ap + ((size_t)(node >> 4) * 1024 + lane * 16 + (node & 15)) * 16) = o.f4;
}

// ---------------- f32 fallback SpMM (row-major A, legacy path) ----------------
__global__ __launch_bounds__(256)
void k_spmm_f32(const float* __restrict__ x, const int* __restrict__ row_start,
                const int* __restrict__ csr_src, const int* __restrict__ deg_out,
                __hip_bfloat16* __restrict__ A, int N) {
    int wid = threadIdx.x >> 6;
    int lane = threadIdx.x & 63;
    int node = blockIdx.x * 4 + wid;
    if (node >= N) return;
    int rs = row_start[node], re = row_start[node + 1];
    float4 acc0 = {0.f, 0.f, 0.f, 0.f};
    float4 acc1 = {0.f, 0.f, 0.f, 0.f};
    const float* xl = x + (size_t)lane * 8;
    for (int j = rs; j < re; j++) {
        int s = csr_src[j];
        float w = rsqrtf((float)max(deg_out[s], 1));
        const float4* p = (const float4*)(xl + (size_t)s * D);
        float4 a = p[0], b = p[1];
        acc0.x += a.x * w; acc0.y += a.y * w; acc0.z += a.z * w; acc0.w += a.w * w;
        acc1.x += b.x * w; acc1.y += b.y * w; acc1.z += b.z * w; acc1.w += b.w * w;
    }
    float rn = rsqrtf((float)max(re - rs, 1));
    union { float4 f4; __hip_bfloat16 h[8]; } o;
    o.h[0] = __float2bfloat16(acc0.x * rn);
    o.h[1] = __float2bfloat16(acc0.y * rn);
    o.h[2] = __float2bfloat16(acc0.z * rn);
    o.h[3] = __float2bfloat16(acc0.w * rn);
    o.h[4] = __float2bfloat16(acc1.x * rn);
    o.h[5] = __float2bfloat16(acc1.y * rn);
    o.h[6] = __float2bfloat16(acc1.z * rn);
    o.h[7] = __float2bfloat16(acc1.w * rn);
    *(float4*)(A + (size_t)node * D + lane * 8) = o.f4;
}

// ---------------- pack W into per-col-chunk MFMA B layout ----------------
// bid = c*128 + kt*8 + ntc ; element (bid, lane, j) =
//   W[kt*32 + (lane>>4)*8 + j][(c*8 + ntc)*16 + (lane&15)]
// gemm3 wave wn reads frag t at kt as the contiguous 1KB at bid = wn*128 + kt*8 + t.
__global__ void k_packw2(const float* __restrict__ W, __hip_bfloat16* __restrict__ Wp) {
    int bid = blockIdx.x;        // 0..511
    int c = bid >> 7, kt = (bid >> 3) & 15, ntc = bid & 7;
    int lane = threadIdx.x;      // 0..63
    int k0 = kt * 32 + (lane >> 4) * 8;
    int n  = (c * 8 + ntc) * 16 + (lane & 15);
    union { float4 f4; __hip_bfloat16 h[8]; } o;
    #pragma unroll
    for (int j = 0; j < 8; j++)
        o.h[j] = __float2bfloat16(W[(size_t)(k0 + j) * D + n]);
    *(float4*)(Wp + ((size_t)bid * 64 + lane) * 8) = o.f4;
}

// legacy pack (fallback path)
__global__ void k_packw(const float* __restrict__ W, __hip_bfloat16* __restrict__ Wp) {
    int tile = blockIdx.x;
    int lane = threadIdx.x;
    int kt = tile >> 5, nt = tile & 31;
    int k0 = kt * 32 + (lane >> 4) * 8;
    int n  = nt * 16 + (lane & 15);
    union { float4 f4; __hip_bfloat16 h[8]; } o;
    #pragma unroll
    for (int j = 0; j < 8; j++)
        o.h[j] = __float2bfloat16(W[(size_t)(k0 + j) * D + n]);
    *(float4*)(Wp + ((size_t)tile * 64 + lane) * 8) = o.f4;
}

// ---------------- fused GEMM + bias + LN + tanh-GELU, NO LDS staging, NO K-loop barriers ----
// 512 thr = 8 waves (wm = wid>>2 in 0..1 : 32-row half; wn = wid&3 : 128-col quarter).
// Block = 64 rows x 512 cols. Per wave: 2 A-frags + 8 B-frags per kt, 16 MFMA/kt.
// A' fragment-major (coalesced 1KB frag loads); Wp packed (coalesced 1KB frag loads).
// W (512KB) is L2-resident per XCD; A streamed once. Compiler pipelines freely.
__global__ __launch_bounds__(512, 4)
void k_gemm3(const __hip_bfloat16* __restrict__ Ap, const __hip_bfloat16* __restrict__ Wp,
             const float* __restrict__ bias, const float* __restrict__ gamma,
             const float* __restrict__ beta, float* __restrict__ out, int M) {
    __shared__ float s_sum[64][4];
    __shared__ float s_sq[64][4];

    int tid = threadIdx.x;
    int wid = tid >> 6, lane = tid & 63;
    int wm = wid >> 2, wn = wid & 3;
    int l4 = lane >> 4, coll = lane & 15;
    int tb = blockIdx.x * 64;
    int rgmax = ((M + 15) >> 4) - 1;

    int rg0 = (tb >> 4) + wm * 2;
    int rgA = min(rg0, rgmax);
    int rgB = min(rg0 + 1, rgmax);
    const char* a0 = (const char*)Ap + (size_t)rgA * 16384 + (size_t)lane * 16;
    const char* a1 = (const char*)Ap + (size_t)rgB * 16384 + (size_t)lane * 16;
    const char* wb = (const char*)Wp + ((size_t)(wn * 128) * 64 + lane) * 16;

    f32x4 acc0[8], acc1[8];
    #pragma unroll
    for (int t = 0; t < 8; t++) { acc0[t] = (f32x4){0,0,0,0}; acc1[t] = (f32x4){0,0,0,0}; }

    for (int kt = 0; kt < 16; kt++) {
        bf16x8 af0 = *(const bf16x8*)(a0 + (size_t)kt * 1024);
        bf16x8 af1 = *(const bf16x8*)(a1 + (size_t)kt * 1024);
        const char* wk = wb + (size_t)kt * 8192;
        #pragma unroll
        for (int t = 0; t < 8; t++) {
            bf16x8 bf = *(const bf16x8*)(wk + (size_t)t * 1024);
            acc0[t] = __builtin_amdgcn_mfma_f32_16x16x32_bf16(af0, bf, acc0[t], 0, 0, 0);
            acc1[t] = __builtin_amdgcn_mfma_f32_16x16x32_bf16(af1, bf, acc1[t], 0, 0, 0);
        }
    }

    // epilogue: bias + LN stats (rows rb = wm*32 + ai*16 + l4*4 + r; cols wn*128 + t*16 + coll)
    float bia[8], gam[8], bet[8];
    #pragma unroll
    for (int t = 0; t < 8; t++) {
        int col = wn * 128 + t * 16 + coll;
        bia[t] = bias[col]; gam[t] = gamma[col]; bet[t] = beta[col];
    }
    #pragma unroll
    for (int ai = 0; ai < 2; ai++) {
        f32x4* acc = ai ? acc1 : acc0;
        #pragma unroll
        for (int r = 0; r < 4; r++) {
            float s = 0.f, q = 0.f;
            #pragma unroll
            for (int t = 0; t < 8; t++) {
                float v = acc[t][r] + bia[t];
                acc[t][r] = v;
                s += v; q += v * v;
            }
            #pragma unroll
            for (int off = 1; off < 16; off <<= 1) {
                s += __shfl_xor(s, off, 64);
                q += __shfl_xor(q, off, 64);
            }
            if (coll == 0) {
                int rb = wm * 32 + ai * 16 + l4 * 4 + r;
                s_sum[rb][wn] = s;
                s_sq[rb][wn] = q;
            }
        }
    }
    __syncthreads();

    #pragma unroll
    for (int ai = 0; ai < 2; ai++) {
        f32x4* acc = ai ? acc1 : acc0;
        #pragma unroll
        for (int r = 0; r < 4; r++) {
            int rb = wm * 32 + ai * 16 + l4 * 4 + r;
            int gr = tb + rb;
            if (gr >= M) continue;
            float s = s_sum[rb][0] + s_sum[rb][1] + s_sum[rb][2] + s_sum[rb][3];
            float q = s_sq[rb][0] + s_sq[rb][1] + s_sq[rb][2] + s_sq[rb][3];
            float mean = s * (1.0f / 512.0f);
            float var = q * (1.0f / 512.0f) - mean * mean;
            float rstd = rsqrtf(fmaxf(var, 0.f) + 1e-5f);
            float* orow = out + (size_t)gr * D + wn * 128 + coll;
            #pragma unroll
            for (int t = 0; t < 8; t++) {
                float y = (acc[t][r] - mean) * rstd * gam[t] + bet[t];
                float yy = y * y;
                float pz = fmaf(yy, -0.1029423374f, -2.3022076728f);
                float e = __builtin_amdgcn_exp2f(y * pz);
                float g = y * __builtin_amdgcn_rcpf(1.0f + e);
                orow[t * 16] = g;
            }
        }
    }
}

// ---------------- legacy fused GEMM (fallback if ws too small) ----------------
__global__ __launch_bounds__(512)
void k_gemm(const __hip_bfloat16* __restrict__ A, const __hip_bfloat16* __restrict__ Wp,
            const float* __restrict__ bias, const float* __restrict__ gamma,
            const float* __restrict__ beta, float* __restrict__ out, int M) {
    int tid = threadIdx.x;
    int wid = tid >> 6, lane = tid & 63;
    int wm = wid >> 2;
    int wn = wid & 3;
    int l4 = lane >> 4, coll = lane & 15;
    int m0 = blockIdx.x * 32 + wm * 16;
    int arow = m0 + coll;
    bool rowok = (arow < M);

    f32x4 acc[8];
    #pragma unroll
    for (int t = 0; t < 8; t++) acc[t] = (f32x4){0.f, 0.f, 0.f, 0.f};

    const bf16x8* wpb = (const bf16x8*)Wp;
    for (int kt = 0; kt < 16; kt++) {
        bf16x8 afrag;
        if (rowok) afrag = *(const bf16x8*)(A + (size_t)arow * D + kt * 32 + l4 * 8);
        else afrag = (bf16x8){0,0,0,0,0,0,0,0};
        const bf16x8* wp = wpb + ((size_t)(kt * 32 + wn * 8) * 64 + lane);
        #pragma unroll
        for (int t = 0; t < 8; t++) {
            bf16x8 bfrag = wp[(size_t)t * 64];
            acc[t] = __builtin_amdgcn_mfma_f32_16x16x32_bf16(afrag, bfrag, acc[t], 0, 0, 0);
        }
    }
    __shared__ float s_sum[32][4];
    __shared__ float s_sq[32][4];
    #pragma unroll
    for (int r = 0; r < 4; r++) {
        float s = 0.f, q = 0.f;
        #pragma unroll
        for (int t = 0; t < 8; t++) {
            int col = wn * 128 + t * 16 + coll;
            float v = acc[t][r] + bias[col];
            acc[t][r] = v;
            s += v; q += v * v;
        }
        #pragma unroll
        for (int off = 1; off < 16; off <<= 1) {
            s += __shfl_xor(s, off, 64);
            q += __shfl_xor(q, off, 64);
        }
        if (coll == 0) {
            int rb = wm * 16 + l4 * 4 + r;
            s_sum[rb][wn] = s;
            s_sq[rb][wn] = q;
        }
    }
    __syncthreads();
    #pragma unroll
    for (int r = 0; r < 4; r++) {
        int rb = wm * 16 + l4 * 4 + r;
        int gr = blockIdx.x * 32 + rb;
        if (gr >= M) continue;
        float s = s_sum[rb][0] + s_sum[rb][1] + s_sum[rb][2] + s_sum[rb][3];
        float q = s_sq[rb][0] + s_sq[rb][1] + s_sq[rb][2] + s_sq[rb][3];
        float mean = s * (1.0f / 512.0f);
        float var = q * (1.0f / 512.0f) - mean * mean;
        float rstd = rsqrtf(fmaxf(var, 0.f) + 1e-5f);
        #pragma unroll
        for (int t = 0; t < 8; t++) {
            int col = wn * 128 + t * 16 + coll;
            float y = (acc[t][r] - mean) * rstd * gamma[col] + beta[col];
            float yy = y * y;
            float pz = fmaf(yy, -0.1029423374f, -2.3022076728f);
            float e = __builtin_amdgcn_exp2f(y * pz);
            out[(size_t)gr * D + col] = y * __builtin_amdgcn_rcpf(1.0f + e);
        }
    }
}

extern "C" void kernel_launch(void* const* d_in, const int* in_sizes, int n_in,
                              void* d_out, int out_size, void* d_ws, size_t ws_size,
                              hipStream_t stream) {
    const float* x     = (const float*)d_in[0];
    const float* W     = (const float*)d_in[1];
    const float* b     = (const float*)d_in[2];
    const float* gamma = (const float*)d_in[3];
    const float* beta  = (const float*)d_in[4];
    const int*   src   = (const int*)d_in[5];
    const int*   dst   = (const int*)d_in[6];
    int N = in_sizes[0] / D;
    int E = in_sizes[5];
    float* out = (float*)d_out;

    int* deg_out   = (int*)d_ws;                 // N
    int* deg_in    = deg_out + N;                // N
    int* row_start = deg_in + N;                 // N+1
    int* cursor    = row_start + N + 1;          // N
    int* partials  = cursor + N;                 // <=64
    int* csr_src   = partials + 64;              // E
    uintptr_t p = (uintptr_t)(csr_src + E);
    p = (p + 255) & ~(uintptr_t)255;
    __hip_bfloat16* A = (__hip_bfloat16*)p;      // N*D bf16 (fragment-major A' / legacy row-major)
    p += (size_t)(((N + 15) / 16) * 16) * D * sizeof(__hip_bfloat16);
    p = (p + 255) & ~(uintptr_t)255;
    __hip_bfloat16* Wp = (__hip_bfloat16*)p;     // D*D bf16
    p += (size_t)D * D * sizeof(__hip_bfloat16);
    p = (p + 255) & ~(uintptr_t)255;
    __hip_bfloat16* xs = (__hip_bfloat16*)p;     // N*D bf16
    size_t need_xs = (p - (uintptr_t)d_ws) + (size_t)N * D * sizeof(__hip_bfloat16);
    bool use_bf16_path = (ws_size >= need_xs);

    hipMemsetAsync(deg_out, 0, (size_t)2 * N * sizeof(int), stream);
    hipMemsetAsync(cursor, 0, (size_t)N * sizeof(int), stream);

    k_hist<<<(E + 255) / 256, 256, 0, stream>>>(src, dst, deg_out, deg_in, E);
    int nb1 = (N + 1023) / 1024;
    k_scan1<<<nb1, 1024, 0, stream>>>(deg_in, row_start, partials, N);
    if (nb1 <= 64)
        k_scan2w<<<1, 64, 0, stream>>>(partials, row_start, nb1, N);
    else
        k_scan2s<<<1, 64, 0, stream>>>(partials, row_start, nb1, N);
    k_scan3<<<(N + 255) / 256, 256, 0, stream>>>(row_start, partials, N);
    k_fill<<<(E + 255) / 256, 256, 0, stream>>>(src, dst, row_start, cursor, csr_src, E);

    if (use_bf16_path) {
        int total16 = N * 64;
        k_scale<<<(total16 + 255) / 256, 256, 0, stream>>>(x, deg_out, xs, total16);
        k_spmm<<<(N + 15) / 16, 1024, 0, stream>>>(xs, row_start, csr_src, A, N);
        k_packw2<<<512, 64, 0, stream>>>(W, Wp);
        k_gemm3<<<(N + 63) / 64, 512, 0, stream>>>(A, Wp, b, gamma, beta, out, N);
    } else {
        k_spmm_f32<<<(N + 3) / 4, 256, 0, stream>>>(x, row_start, csr_src, deg_out, A, N);
        k_packw<<<512, 64, 0, stream>>>(W, Wp);
        k_gemm<<<(N + 31) / 32, 512, 0, stream>>>(A, Wp, b, gamma, beta, out, N);
    }
}